// Round 3
// baseline (201.821 us; speedup 1.0000x reference)
//
#include <hip/hip_runtime.h>
#include <hip/hip_bf16.h>
#include <hip/hip_cooperative_groups.h>

namespace cg = cooperative_groups;

// GCN SpMM: out[i,d] = sum_{e: rows[e]==i} vals[e] * embeds[cols[e], d]
// rows sorted ascending. E=1.6M, N=100k, D=64.
//
// Round 10: single cooperative kernel.
//   Phase A (grid-stride): f32->bf16 table (12.8 MB in d_ws) + CSR row_ptr.
//   grid.sync()  (agent-scope release/acquire covers cross-XCD visibility)
//   Phase B (grid-stride over node octets): 8-lane subgroups, wave-private
//   LDS staging of cols/vals, unroll-8 gather pipeline (as round 9).
// Rationale: R8 (fewer VMEM instrs) and R9 (2x MLP) were both ~neutral ->
// spmm is neither issue- nor latency-bound; the remaining unexplained time
// is inter-dispatch overhead, and the fused kernel surfaces in rocprof
// top-5 (> 44 us fills) so next round finally sees its counters.
// Fallback: if cooperative launch fails (capture unsupported), launch the
// proven two-kernel path instead.

constexpr int D = 64;

__device__ __forceinline__ unsigned bf16rnd(unsigned u) {
    // round-to-nearest-even f32 -> bf16 (low 16 bits)
    return (u + 0x7FFFu + ((u >> 16) & 1u)) >> 16;
}
__device__ __forceinline__ float bflo(unsigned w) {
    union { unsigned u; float f; } x; x.u = w << 16; return x.f;
}
__device__ __forceinline__ float bfhi(unsigned w) {
    union { unsigned u; float f; } x; x.u = w & 0xFFFF0000u; return x.f;
}

// ---------------------------------------------------------------- fused ---
__global__ __launch_bounds__(256, 4) void fused_kernel(
    const int* __restrict__ rows,
    const int* __restrict__ cols,
    const float* __restrict__ vals,
    const uint4* __restrict__ src,      // f32 embeds as uint4 pairs
    uint4* __restrict__ ebf4,           // bf16 table [N,64] = 8 uint4/row
    int* __restrict__ row_ptr,          // [N+1]
    float4* __restrict__ out4,          // [N,16]
    int n8, int n_edges, int n_nodes)
{
    const int tid  = blockIdx.x * 256 + threadIdx.x;
    const int nthr = gridDim.x * 256;

    // Phase A1: f32 -> bf16 table
    for (int i = tid; i < n8; i += nthr) {
        uint4 a = src[2 * i];
        uint4 b = src[2 * i + 1];
        uint4 o;
        o.x = bf16rnd(a.x) | (bf16rnd(a.y) << 16);
        o.y = bf16rnd(a.z) | (bf16rnd(a.w) << 16);
        o.z = bf16rnd(b.x) | (bf16rnd(b.y) << 16);
        o.w = bf16rnd(b.z) | (bf16rnd(b.w) << 16);
        ebf4[i] = o;
    }
    // Phase A2: CSR row_ptr from sorted rows
    for (int e = tid; e < n_edges; e += nthr) {
        int r_cur  = rows[e];
        int r_prev = (e == 0) ? -1 : rows[e - 1];
        for (int r = r_prev + 1; r <= r_cur; ++r) row_ptr[r] = e;
        if (e == n_edges - 1)
            for (int r = r_cur + 1; r <= n_nodes; ++r) row_ptr[r] = n_edges;
    }

    cg::this_grid().sync();

    // Phase B: node-centric SpMM, grid-stride over octets of nodes
    constexpr int CHUNK = 256;
    __shared__ int   s_cols[4][CHUNK];    // 4 waves/block, wave-private
    __shared__ float s_vals[4][CHUNK];

    const int lane   = threadIdx.x & 63;
    const int t      = lane & 7;          // 16B chunk within row
    const int s      = lane >> 3;         // subgroup (node) within wave
    const int w      = threadIdx.x >> 6;  // wave within block
    const int nwaves = gridDim.x * 4;
    const int noct   = (n_nodes + 7) / 8;

    for (int oct = blockIdx.x * 4 + w; oct < noct; oct += nwaves) {
        const int nb    = oct * 8;
        const int node  = nb + s;
        const int nbhi  = (nb + 8 <= n_nodes) ? nb + 8 : n_nodes;
        const int wbase = row_ptr[nb];    // wave's contiguous edge span
        const int wend  = row_ptr[nbhi];
        const bool live = (node < n_nodes);
        const int lo    = live ? row_ptr[node]     : wend;
        const int hi    = live ? row_ptr[node + 1] : wend;

        float4 acc0 = make_float4(0.f, 0.f, 0.f, 0.f);
        float4 acc1 = make_float4(0.f, 0.f, 0.f, 0.f);

        for (int cbase = wbase; cbase < wend; cbase += CHUNK) {
            // cooperative, coalesced staging of this wave's edge chunk
            #pragma unroll
            for (int j = 0; j < CHUNK; j += 64) {
                if (cbase + j >= wend) break;     // wave-uniform early out
                int idx = cbase + j + lane;
                if (idx < wend) {
                    s_cols[w][j + lane] = cols[idx];
                    s_vals[w][j + lane] = vals[idx];
                }
            }
            __builtin_amdgcn_wave_barrier();  // pin ds_writes before ds_reads

            const int cend = (cbase + CHUNK < wend) ? cbase + CHUNK : wend;
            int e0 = (lo > cbase) ? lo : cbase;
            int e1 = (hi < cend)  ? hi : cend;

            for (int e = e0; e < e1; e += 8) {
                const int last = e1 - 1;
                int i0 = e - cbase;
                int i1 = ((e + 1 <= last) ? e + 1 : last) - cbase;
                int i2 = ((e + 2 <= last) ? e + 2 : last) - cbase;
                int i3 = ((e + 3 <= last) ? e + 3 : last) - cbase;
                int i4 = ((e + 4 <= last) ? e + 4 : last) - cbase;
                int i5 = ((e + 5 <= last) ? e + 5 : last) - cbase;
                int i6 = ((e + 6 <= last) ? e + 6 : last) - cbase;
                int i7 = ((e + 7 <= last) ? e + 7 : last) - cbase;

                int c0 = s_cols[w][i0], c1 = s_cols[w][i1];
                int c2 = s_cols[w][i2], c3 = s_cols[w][i3];
                int c4 = s_cols[w][i4], c5 = s_cols[w][i5];
                int c6 = s_cols[w][i6], c7 = s_cols[w][i7];

                float v0 = s_vals[w][i0];
                float v1 = (e + 1 < e1) ? s_vals[w][i1] : 0.f;
                float v2 = (e + 2 < e1) ? s_vals[w][i2] : 0.f;
                float v3 = (e + 3 < e1) ? s_vals[w][i3] : 0.f;
                float v4 = (e + 4 < e1) ? s_vals[w][i4] : 0.f;
                float v5 = (e + 5 < e1) ? s_vals[w][i5] : 0.f;
                float v6 = (e + 6 < e1) ? s_vals[w][i6] : 0.f;
                float v7 = (e + 7 < e1) ? s_vals[w][i7] : 0.f;

                uint4 m0 = ebf4[c0 * 8 + t];
                uint4 m1 = ebf4[c1 * 8 + t];
                uint4 m2 = ebf4[c2 * 8 + t];
                uint4 m3 = ebf4[c3 * 8 + t];
                uint4 m4 = ebf4[c4 * 8 + t];
                uint4 m5 = ebf4[c5 * 8 + t];
                uint4 m6 = ebf4[c6 * 8 + t];
                uint4 m7 = ebf4[c7 * 8 + t];

                acc0.x += v0 * bflo(m0.x); acc0.y += v0 * bfhi(m0.x);
                acc0.z += v0 * bflo(m0.y); acc0.w += v0 * bfhi(m0.y);
                acc1.x += v0 * bflo(m0.z); acc1.y += v0 * bfhi(m0.z);
                acc1.z += v0 * bflo(m0.w); acc1.w += v0 * bfhi(m0.w);

                acc0.x += v1 * bflo(m1.x); acc0.y += v1 * bfhi(m1.x);
                acc0.z += v1 * bflo(m1.y); acc0.w += v1 * bfhi(m1.y);
                acc1.x += v1 * bflo(m1.z); acc1.y += v1 * bfhi(m1.z);
                acc1.z += v1 * bflo(m1.w); acc1.w += v1 * bfhi(m1.w);

                acc0.x += v2 * bflo(m2.x); acc0.y += v2 * bfhi(m2.x);
                acc0.z += v2 * bflo(m2.y); acc0.w += v2 * bfhi(m2.y);
                acc1.x += v2 * bflo(m2.z); acc1.y += v2 * bfhi(m2.z);
                acc1.z += v2 * bflo(m2.w); acc1.w += v2 * bfhi(m2.w);

                acc0.x += v3 * bflo(m3.x); acc0.y += v3 * bfhi(m3.x);
                acc0.z += v3 * bflo(m3.y); acc0.w += v3 * bfhi(m3.y);
                acc1.x += v3 * bflo(m3.z); acc1.y += v3 * bfhi(m3.z);
                acc1.z += v3 * bflo(m3.w); acc1.w += v3 * bfhi(m3.w);

                acc0.x += v4 * bflo(m4.x); acc0.y += v4 * bfhi(m4.x);
                acc0.z += v4 * bflo(m4.y); acc0.w += v4 * bfhi(m4.y);
                acc1.x += v4 * bflo(m4.z); acc1.y += v4 * bfhi(m4.z);
                acc1.z += v4 * bflo(m4.w); acc1.w += v4 * bfhi(m4.w);

                acc0.x += v5 * bflo(m5.x); acc0.y += v5 * bfhi(m5.x);
                acc0.z += v5 * bflo(m5.y); acc0.w += v5 * bfhi(m5.y);
                acc1.x += v5 * bflo(m5.z); acc1.y += v5 * bfhi(m5.z);
                acc1.z += v5 * bflo(m5.w); acc1.w += v5 * bfhi(m5.w);

                acc0.x += v6 * bflo(m6.x); acc0.y += v6 * bfhi(m6.x);
                acc0.z += v6 * bflo(m6.y); acc0.w += v6 * bfhi(m6.y);
                acc1.x += v6 * bflo(m6.z); acc1.y += v6 * bfhi(m6.z);
                acc1.z += v6 * bflo(m6.w); acc1.w += v6 * bfhi(m6.w);

                acc0.x += v7 * bflo(m7.x); acc0.y += v7 * bfhi(m7.x);
                acc0.z += v7 * bflo(m7.y); acc0.w += v7 * bfhi(m7.y);
                acc1.x += v7 * bflo(m7.z); acc1.y += v7 * bfhi(m7.z);
                acc1.z += v7 * bflo(m7.w); acc1.w += v7 * bfhi(m7.w);
            }
            __builtin_amdgcn_wave_barrier();  // next chunk's writes after reads
        }

        if (live) {
            long ob = (long)node * 16 + 2 * t;   // features [8t, 8t+8)
            out4[ob]     = acc0;
            out4[ob + 1] = acc1;
        }
    }
}

// ------------------------------------------------- fallback (round-9 path) ---
__global__ __launch_bounds__(256) void prep_kernel(
    const uint4* __restrict__ src, uint4* __restrict__ dst, int n8,
    const int* __restrict__ rows, int* __restrict__ row_ptr,
    int n_edges, int n_nodes, int cvt_blocks)
{
    if ((int)blockIdx.x < cvt_blocks) {
        int i = blockIdx.x * 256 + threadIdx.x;
        if (i >= n8) return;
        uint4 a = src[2 * i];
        uint4 b = src[2 * i + 1];
        uint4 o;
        o.x = bf16rnd(a.x) | (bf16rnd(a.y) << 16);
        o.y = bf16rnd(a.z) | (bf16rnd(a.w) << 16);
        o.z = bf16rnd(b.x) | (bf16rnd(b.y) << 16);
        o.w = bf16rnd(b.z) | (bf16rnd(b.w) << 16);
        dst[i] = o;
    } else {
        int e = (blockIdx.x - cvt_blocks) * 256 + threadIdx.x;
        if (e >= n_edges) return;
        int r_cur  = rows[e];
        int r_prev = (e == 0) ? -1 : rows[e - 1];
        for (int r = r_prev + 1; r <= r_cur; ++r) row_ptr[r] = e;
        if (e == n_edges - 1)
            for (int r = r_cur + 1; r <= n_nodes; ++r) row_ptr[r] = n_edges;
    }
}

__global__ __launch_bounds__(256, 4) void spmm_node_kernel(
    const int* __restrict__ row_ptr, const int* __restrict__ cols,
    const float* __restrict__ vals, const uint4* __restrict__ ebf4,
    float4* __restrict__ out4, int n_nodes)
{
    constexpr int CHUNK = 256;
    __shared__ int   s_cols[4][CHUNK];
    __shared__ float s_vals[4][CHUNK];

    const int lane = threadIdx.x & 63;
    const int t    = lane & 7;
    const int s    = lane >> 3;
    const int w    = threadIdx.x >> 6;
    const int wave = blockIdx.x * (blockDim.x >> 6) + w;
    const int node = wave * 8 + s;
    if (node >= n_nodes) return;

    const int nb    = wave * 8;
    const int nbhi  = (nb + 8 <= n_nodes) ? nb + 8 : n_nodes;
    const int wbase = row_ptr[nb];
    const int wend  = row_ptr[nbhi];
    const int lo    = row_ptr[node];
    const int hi    = row_ptr[node + 1];

    float4 acc0 = make_float4(0.f, 0.f, 0.f, 0.f);
    float4 acc1 = make_float4(0.f, 0.f, 0.f, 0.f);

    for (int cbase = wbase; cbase < wend; cbase += CHUNK) {
        #pragma unroll
        for (int j = 0; j < CHUNK; j += 64) {
            if (cbase + j >= wend) break;
            int idx = cbase + j + lane;
            if (idx < wend) {
                s_cols[w][j + lane] = cols[idx];
                s_vals[w][j + lane] = vals[idx];
            }
        }
        __builtin_amdgcn_wave_barrier();

        const int cend = (cbase + CHUNK < wend) ? cbase + CHUNK : wend;
        int e0 = (lo > cbase) ? lo : cbase;
        int e1 = (hi < cend)  ? hi : cend;

        for (int e = e0; e < e1; e += 4) {
            const int last = e1 - 1;
            int i0 = e - cbase;
            int i1 = ((e + 1 <= last) ? e + 1 : last) - cbase;
            int i2 = ((e + 2 <= last) ? e + 2 : last) - cbase;
            int i3 = ((e + 3 <= last) ? e + 3 : last) - cbase;

            int c0 = s_cols[w][i0], c1 = s_cols[w][i1];
            int c2 = s_cols[w][i2], c3 = s_cols[w][i3];
            float v0 = s_vals[w][i0];
            float v1 = (e + 1 < e1) ? s_vals[w][i1] : 0.f;
            float v2 = (e + 2 < e1) ? s_vals[w][i2] : 0.f;
            float v3 = (e + 3 < e1) ? s_vals[w][i3] : 0.f;

            uint4 m0 = ebf4[c0 * 8 + t];
            uint4 m1 = ebf4[c1 * 8 + t];
            uint4 m2 = ebf4[c2 * 8 + t];
            uint4 m3 = ebf4[c3 * 8 + t];

            acc0.x += v0 * bflo(m0.x); acc0.y += v0 * bfhi(m0.x);
            acc0.z += v0 * bflo(m0.y); acc0.w += v0 * bfhi(m0.y);
            acc1.x += v0 * bflo(m0.z); acc1.y += v0 * bfhi(m0.z);
            acc1.z += v0 * bflo(m0.w); acc1.w += v0 * bfhi(m0.w);

            acc0.x += v1 * bflo(m1.x); acc0.y += v1 * bfhi(m1.x);
            acc0.z += v1 * bflo(m1.y); acc0.w += v1 * bfhi(m1.y);
            acc1.x += v1 * bflo(m1.z); acc1.y += v1 * bfhi(m1.z);
            acc1.z += v1 * bflo(m1.w); acc1.w += v1 * bfhi(m1.w);

            acc0.x += v2 * bflo(m2.x); acc0.y += v2 * bfhi(m2.x);
            acc0.z += v2 * bflo(m2.y); acc0.w += v2 * bfhi(m2.y);
            acc1.x += v2 * bflo(m2.z); acc1.y += v2 * bfhi(m2.z);
            acc1.z += v2 * bflo(m2.w); acc1.w += v2 * bfhi(m2.w);

            acc0.x += v3 * bflo(m3.x); acc0.y += v3 * bfhi(m3.x);
            acc0.z += v3 * bflo(m3.y); acc0.w += v3 * bfhi(m3.y);
            acc1.x += v3 * bflo(m3.z); acc1.y += v3 * bfhi(m3.z);
            acc1.z += v3 * bflo(m3.w); acc1.w += v3 * bfhi(m3.w);
        }
        __builtin_amdgcn_wave_barrier();
    }

    long ob = (long)node * 16 + 2 * t;
    out4[ob]     = acc0;
    out4[ob + 1] = acc1;
}

// ------------------------------------------------------------------ host ---
extern "C" void kernel_launch(void* const* d_in, const int* in_sizes, int n_in,
                              void* d_out, int out_size, void* d_ws, size_t ws_size,
                              hipStream_t stream) {
    const int*   rows   = (const int*)d_in[0];
    const int*   cols   = (const int*)d_in[1];
    const float* vals   = (const float*)d_in[2];
    const float* embeds = (const float*)d_in[3];
    float4*      out4   = (float4*)d_out;

    const int n_edges = in_sizes[0];
    const int n_nodes = out_size / D;                 // 100000
    const int n_feat  = in_sizes[3];                  // 6,400,000

    char*  ws        = (char*)d_ws;
    uint4* ebf_table = (uint4*)ws;                    // 12.8 MB bf16 table
    int*   row_ptr   = (int*)(ws + (size_t)n_feat * 2);

    int n8 = n_feat / 8;                              // 800,000 groups

    const uint4* src = (const uint4*)embeds;
    void* args[] = { (void*)&rows, (void*)&cols, (void*)&vals, (void*)&src,
                     (void*)&ebf_table, (void*)&row_ptr, (void*)&out4,
                     (void*)&n8, (void*)&n_edges, (void*)&n_nodes };

    // 1024 blocks co-resident with __launch_bounds__(256,4) (4 blocks/CU x 256)
    hipError_t err = hipLaunchCooperativeKernel(
        (const void*)fused_kernel, dim3(1024), dim3(256), args, 0, stream);

    if (err != hipSuccess) {
        // fallback: proven two-kernel path (round 9)
        int cvt_blocks = (n8 + 255) / 256;
        int row_blocks = (n_edges + 255) / 256;
        prep_kernel<<<cvt_blocks + row_blocks, 256, 0, stream>>>(
            src, ebf_table, n8, rows, row_ptr, n_edges, n_nodes, cvt_blocks);
        int waves  = (n_nodes + 7) / 8;
        int blocks = (waves + 3) / 4;
        spmm_node_kernel<<<blocks, 256, 0, stream>>>(
            row_ptr, cols, vals, ebf_table, out4, n_nodes);
    }
}

// Round 5
// 149.071 us; speedup vs baseline: 1.3539x; 1.3539x over previous
//
#include <hip/hip_runtime.h>

// GCN SpMM: out[i,d] = sum_{e: rows[e]==i} vals[e] * embeds[cols[e], d]
// rows sorted ascending. E=1.6M, N=100k, D=64.
//
// Round 12 == Round 11 resubmitted (bench infra failed twice; no kernel
// verdict). Design audit found no fault/hang path; resubmitting unchanged
// to get the measurement rather than mutating blind.
//
// Round 11: SINGLE dispatch, zero prep, f32 gathers.
// Rationale from R10 counters (fused kernel finally visible): VALUBusy 12%,
// HBM 16%, bank conflicts ~0 -> the gather pipe is latency-bound with large
// BW headroom. Therefore the bf16 table's byte-halving is near-worthless,
// while its cost is real and serial: 38 MB of prep traffic + 12.8 MB table
// HBM refetch after every workspace poison + one dispatch boundary.
//   - Gather f32 embeds directly (exact accuracy, absmax ~1e-5).
//   - CSR bounds via 5 parallel lower_bound searches over sorted rows[]
//     (lanes 0..4 per wave, ~21 dependent L1/L2-hot loads, hidden by
//     other resident waves' gathers). No row_ptr, no workspace use.
//   - 16-lane subgroups (4 nodes/wave): lane t owns float4 feats [4t,4t+4);
//     each gather instruction covers 4 rows x 256 B = 1 KB.
//   - Wave-private LDS staging of cols/vals (R8, proven) + unroll-8 (R9).
// Cooperative fusion (R10) is dead: capped occupancy at 16 waves/CU and
// added ~90 us of non-captured launch overhead.

constexpr int D = 64;

__global__ __launch_bounds__(256, 4) void spmm_f32_kernel(
    const int* __restrict__ rows,
    const int* __restrict__ cols,
    const float* __restrict__ vals,
    const float4* __restrict__ emb4,   // f32 embeds [N,64] = 16 float4/row
    float4* __restrict__ out4,         // [N,16] float4 view
    int n_edges, int n_nodes)
{
    constexpr int CHUNK = 256;            // edges staged per wave per pass
    __shared__ int   s_cols[4][CHUNK];    // 4 waves/block, wave-private
    __shared__ float s_vals[4][CHUNK];

    const int lane = threadIdx.x & 63;
    const int t    = lane & 15;           // float4 slot within row (0..15)
    const int s    = lane >> 4;           // subgroup (node) within wave (0..3)
    const int w    = threadIdx.x >> 6;    // wave within block
    const int wave = blockIdx.x * 4 + w;
    const int nb   = wave * 4;            // first node of this wave's quad
    if (nb >= n_nodes) return;

    // ---- per-wave CSR bounds: lanes 0..4 lower_bound(nb+i) on sorted rows
    int target = nb + (lane < 4 ? lane : 4);
    if (target > n_nodes) target = n_nodes;
    int sl = 0, sh = n_edges;
    while (sl < sh) {
        int mid = (sl + sh) >> 1;
        if (rows[mid] < target) sl = mid + 1; else sh = mid;
    }
    const int wbase = __shfl(sl, 0);      // wave's contiguous edge span
    const int wend  = __shfl(sl, 4);
    const int lo    = __shfl(sl, s);      // this subgroup's node bounds
    const int hi    = __shfl(sl, s + 1);
    const int node  = nb + s;
    const bool live = (node < n_nodes);

    float4 acc = make_float4(0.f, 0.f, 0.f, 0.f);

    for (int cbase = wbase; cbase < wend; cbase += CHUNK) {
        // ---- cooperative, coalesced staging of this wave's edge chunk ----
        #pragma unroll
        for (int j = 0; j < CHUNK; j += 64) {
            if (cbase + j >= wend) break;         // wave-uniform early out
            int idx = cbase + j + lane;
            if (idx < wend) {
                s_cols[w][j + lane] = cols[idx];
                s_vals[w][j + lane] = vals[idx];
            }
        }
        __builtin_amdgcn_wave_barrier();  // pin ds_writes before ds_reads

        const int cend = (cbase + CHUNK < wend) ? cbase + CHUNK : wend;
        int e0 = (lo > cbase) ? lo : cbase;       // this node's slice of chunk
        int e1 = (hi < cend)  ? hi : cend;

        for (int e = e0; e < e1; e += 8) {
            const int last = e1 - 1;
            int i0 = e - cbase;
            int i1 = ((e + 1 <= last) ? e + 1 : last) - cbase;
            int i2 = ((e + 2 <= last) ? e + 2 : last) - cbase;
            int i3 = ((e + 3 <= last) ? e + 3 : last) - cbase;
            int i4 = ((e + 4 <= last) ? e + 4 : last) - cbase;
            int i5 = ((e + 5 <= last) ? e + 5 : last) - cbase;
            int i6 = ((e + 6 <= last) ? e + 6 : last) - cbase;
            int i7 = ((e + 7 <= last) ? e + 7 : last) - cbase;

            int c0 = s_cols[w][i0], c1 = s_cols[w][i1];
            int c2 = s_cols[w][i2], c3 = s_cols[w][i3];
            int c4 = s_cols[w][i4], c5 = s_cols[w][i5];
            int c6 = s_cols[w][i6], c7 = s_cols[w][i7];

            float v0 = s_vals[w][i0];
            float v1 = (e + 1 < e1) ? s_vals[w][i1] : 0.f;
            float v2 = (e + 2 < e1) ? s_vals[w][i2] : 0.f;
            float v3 = (e + 3 < e1) ? s_vals[w][i3] : 0.f;
            float v4 = (e + 4 < e1) ? s_vals[w][i4] : 0.f;
            float v5 = (e + 5 < e1) ? s_vals[w][i5] : 0.f;
            float v6 = (e + 6 < e1) ? s_vals[w][i6] : 0.f;
            float v7 = (e + 7 < e1) ? s_vals[w][i7] : 0.f;

            // 8 independent dwordx4 gathers in flight; each covers 4 rows
            float4 m0 = emb4[c0 * 16 + t];
            float4 m1 = emb4[c1 * 16 + t];
            float4 m2 = emb4[c2 * 16 + t];
            float4 m3 = emb4[c3 * 16 + t];
            float4 m4 = emb4[c4 * 16 + t];
            float4 m5 = emb4[c5 * 16 + t];
            float4 m6 = emb4[c6 * 16 + t];
            float4 m7 = emb4[c7 * 16 + t];

            acc.x += v0 * m0.x; acc.y += v0 * m0.y;
            acc.z += v0 * m0.z; acc.w += v0 * m0.w;

            acc.x += v1 * m1.x; acc.y += v1 * m1.y;
            acc.z += v1 * m1.z; acc.w += v1 * m1.w;

            acc.x += v2 * m2.x; acc.y += v2 * m2.y;
            acc.z += v2 * m2.z; acc.w += v2 * m2.w;

            acc.x += v3 * m3.x; acc.y += v3 * m3.y;
            acc.z += v3 * m3.z; acc.w += v3 * m3.w;

            acc.x += v4 * m4.x; acc.y += v4 * m4.y;
            acc.z += v4 * m4.z; acc.w += v4 * m4.w;

            acc.x += v5 * m5.x; acc.y += v5 * m5.y;
            acc.z += v5 * m5.z; acc.w += v5 * m5.w;

            acc.x += v6 * m6.x; acc.y += v6 * m6.y;
            acc.z += v6 * m6.z; acc.w += v6 * m6.w;

            acc.x += v7 * m7.x; acc.y += v7 * m7.y;
            acc.z += v7 * m7.z; acc.w += v7 * m7.w;
        }
        __builtin_amdgcn_wave_barrier();  // next chunk's writes after reads
    }

    if (live) {
        out4[(long)node * 16 + t] = acc;  // 16 lanes x 16 B contiguous per node
    }
}

// ------------------------------------------------------------------ host ---
extern "C" void kernel_launch(void* const* d_in, const int* in_sizes, int n_in,
                              void* d_out, int out_size, void* d_ws, size_t ws_size,
                              hipStream_t stream) {
    const int*   rows   = (const int*)d_in[0];
    const int*   cols   = (const int*)d_in[1];
    const float* vals   = (const float*)d_in[2];
    const float* embeds = (const float*)d_in[3];
    float4*      out4   = (float4*)d_out;

    const int n_edges = in_sizes[0];
    const int n_nodes = out_size / D;                 // 100000

    (void)d_ws; (void)ws_size; (void)n_in;

    // one wave per 4 nodes, 4 waves per block
    int waves  = (n_nodes + 3) / 4;                   // 25000
    int blocks = (waves + 3) / 4;                     // 6250
    spmm_f32_kernel<<<blocks, 256, 0, stream>>>(
        rows, cols, vals, (const float4*)embeds, out4, n_edges, n_nodes);
}

// Round 6
// 129.841 us; speedup vs baseline: 1.5544x; 1.1481x over previous
//
#include <hip/hip_runtime.h>

// GCN SpMM: out[i,d] = sum_{e: rows[e]==i} vals[e] * embeds[cols[e], d]
// rows sorted ascending. E=1.6M, N=100k, D=64.
//
// Round 13: bf16 gathers + convert-only prep + nontemporal streaming.
// R12 (f32 gathers) proved the kernel is fabric-BW-bound on L2-miss bytes:
// FETCH 185 MB at ~2.8 TB/s random-sector service == kernel time. So:
//   - bf16 table (halves row size to 128 B -> halves miss traffic; absmax
//     0.0625 known-pass from R7/R9).
//   - prep = pure f32->bf16 convert (25.6 MB R + 12.8 MB W). row_ptr is
//     GONE: spmm derives bounds from 9 per-wave binary searches on sorted
//     rows[] (mechanism proven in R12, cost hidden under gathers).
//   - touch-once streams (cols/vals staging loads, out stores) use
//     nontemporal hints so they stop evicting the 16x-reused table from
//     the 4-MiB per-XCD L2 -> directly attacks the ~23% bf16 miss rate.
//   - spmm: 8-lane subgroups (8 nodes/wave), wave-private LDS staging,
//     unroll-8 gather pipeline (all proven R8/R9).

constexpr int D = 64;

typedef float v4f __attribute__((ext_vector_type(4)));

__device__ __forceinline__ unsigned bf16rnd(unsigned u) {
    // round-to-nearest-even f32 -> bf16 (low 16 bits)
    return (u + 0x7FFFu + ((u >> 16) & 1u)) >> 16;
}
__device__ __forceinline__ float bflo(unsigned w) {
    union { unsigned u; float f; } x; x.u = w << 16; return x.f;
}
__device__ __forceinline__ float bfhi(unsigned w) {
    union { unsigned u; float f; } x; x.u = w & 0xFFFF0000u; return x.f;
}

// ---- prep: f32 embeds -> bf16 table (convert only, no CSR build) --------
__global__ __launch_bounds__(256) void prep_kernel(
    const uint4* __restrict__ src,   // f32 embeds as uint4 (2 per 8-float group)
    uint4* __restrict__ dst,         // bf16 table as uint4 (8 bf16)
    int n8)
{
    int i = blockIdx.x * 256 + threadIdx.x;
    if (i >= n8) return;
    uint4 a = src[2 * i];
    uint4 b = src[2 * i + 1];
    uint4 o;
    o.x = bf16rnd(a.x) | (bf16rnd(a.y) << 16);
    o.y = bf16rnd(a.z) | (bf16rnd(a.w) << 16);
    o.z = bf16rnd(b.x) | (bf16rnd(b.y) << 16);
    o.w = bf16rnd(b.z) | (bf16rnd(b.w) << 16);
    dst[i] = o;
}

// ---- spmm: node-centric, bf16 gathers, search-derived bounds ------------
__global__ __launch_bounds__(256, 4) void spmm_node_kernel(
    const int* __restrict__ rows,
    const int* __restrict__ cols,
    const float* __restrict__ vals,
    const uint4* __restrict__ ebf4,       // bf16 [N,64]: row = 8 uint4
    float4* __restrict__ out4,            // [N,16] float4 view
    int n_edges, int n_nodes)
{
    constexpr int CHUNK = 256;            // edges staged per wave per pass
    __shared__ int   s_cols[4][CHUNK];    // 4 waves/block, wave-private
    __shared__ float s_vals[4][CHUNK];

    const int lane = threadIdx.x & 63;
    const int t    = lane & 7;            // 16B chunk within row (0..7)
    const int s    = lane >> 3;           // subgroup (node) within wave (0..7)
    const int w    = threadIdx.x >> 6;    // wave within block
    const int wave = blockIdx.x * 4 + w;
    const int nb   = wave * 8;            // first node of this wave's octet
    if (nb >= n_nodes) return;

    // per-wave CSR bounds: lanes 0..8 lower_bound(nb+i) on sorted rows
    int target = nb + (lane < 8 ? lane : 8);
    if (target > n_nodes) target = n_nodes;
    int sl = 0, sh = n_edges;
    while (sl < sh) {
        int mid = (sl + sh) >> 1;
        if (rows[mid] < target) sl = mid + 1; else sh = mid;
    }
    const int wbase = __shfl(sl, 0);      // wave's contiguous edge span
    const int wend  = __shfl(sl, 8);
    const int lo    = __shfl(sl, s);      // this subgroup's node bounds
    const int hi    = __shfl(sl, s + 1);
    const int node  = nb + s;
    const bool live = (node < n_nodes);

    float4 acc0 = make_float4(0.f, 0.f, 0.f, 0.f);
    float4 acc1 = make_float4(0.f, 0.f, 0.f, 0.f);

    for (int cbase = wbase; cbase < wend; cbase += CHUNK) {
        // cooperative, coalesced staging; nontemporal (touch-once streams)
        #pragma unroll
        for (int j = 0; j < CHUNK; j += 64) {
            if (cbase + j >= wend) break;         // wave-uniform early out
            int idx = cbase + j + lane;
            if (idx < wend) {
                s_cols[w][j + lane] = __builtin_nontemporal_load(&cols[idx]);
                s_vals[w][j + lane] = __builtin_nontemporal_load(&vals[idx]);
            }
        }
        __builtin_amdgcn_wave_barrier();  // pin ds_writes before ds_reads

        const int cend = (cbase + CHUNK < wend) ? cbase + CHUNK : wend;
        int e0 = (lo > cbase) ? lo : cbase;       // this node's slice of chunk
        int e1 = (hi < cend)  ? hi : cend;

        for (int e = e0; e < e1; e += 8) {
            const int last = e1 - 1;
            int i0 = e - cbase;
            int i1 = ((e + 1 <= last) ? e + 1 : last) - cbase;
            int i2 = ((e + 2 <= last) ? e + 2 : last) - cbase;
            int i3 = ((e + 3 <= last) ? e + 3 : last) - cbase;
            int i4 = ((e + 4 <= last) ? e + 4 : last) - cbase;
            int i5 = ((e + 5 <= last) ? e + 5 : last) - cbase;
            int i6 = ((e + 6 <= last) ? e + 6 : last) - cbase;
            int i7 = ((e + 7 <= last) ? e + 7 : last) - cbase;

            int c0 = s_cols[w][i0], c1 = s_cols[w][i1];
            int c2 = s_cols[w][i2], c3 = s_cols[w][i3];
            int c4 = s_cols[w][i4], c5 = s_cols[w][i5];
            int c6 = s_cols[w][i6], c7 = s_cols[w][i7];

            float v0 = s_vals[w][i0];
            float v1 = (e + 1 < e1) ? s_vals[w][i1] : 0.f;
            float v2 = (e + 2 < e1) ? s_vals[w][i2] : 0.f;
            float v3 = (e + 3 < e1) ? s_vals[w][i3] : 0.f;
            float v4 = (e + 4 < e1) ? s_vals[w][i4] : 0.f;
            float v5 = (e + 5 < e1) ? s_vals[w][i5] : 0.f;
            float v6 = (e + 6 < e1) ? s_vals[w][i6] : 0.f;
            float v7 = (e + 7 < e1) ? s_vals[w][i7] : 0.f;

            // 8 independent dwordx4 gathers in flight; each covers 8 rows
            uint4 m0 = ebf4[c0 * 8 + t];
            uint4 m1 = ebf4[c1 * 8 + t];
            uint4 m2 = ebf4[c2 * 8 + t];
            uint4 m3 = ebf4[c3 * 8 + t];
            uint4 m4 = ebf4[c4 * 8 + t];
            uint4 m5 = ebf4[c5 * 8 + t];
            uint4 m6 = ebf4[c6 * 8 + t];
            uint4 m7 = ebf4[c7 * 8 + t];

            acc0.x += v0 * bflo(m0.x); acc0.y += v0 * bfhi(m0.x);
            acc0.z += v0 * bflo(m0.y); acc0.w += v0 * bfhi(m0.y);
            acc1.x += v0 * bflo(m0.z); acc1.y += v0 * bfhi(m0.z);
            acc1.z += v0 * bflo(m0.w); acc1.w += v0 * bfhi(m0.w);

            acc0.x += v1 * bflo(m1.x); acc0.y += v1 * bfhi(m1.x);
            acc0.z += v1 * bflo(m1.y); acc0.w += v1 * bfhi(m1.y);
            acc1.x += v1 * bflo(m1.z); acc1.y += v1 * bfhi(m1.z);
            acc1.z += v1 * bflo(m1.w); acc1.w += v1 * bfhi(m1.w);

            acc0.x += v2 * bflo(m2.x); acc0.y += v2 * bfhi(m2.x);
            acc0.z += v2 * bflo(m2.y); acc0.w += v2 * bfhi(m2.y);
            acc1.x += v2 * bflo(m2.z); acc1.y += v2 * bfhi(m2.z);
            acc1.z += v2 * bflo(m2.w); acc1.w += v2 * bfhi(m2.w);

            acc0.x += v3 * bflo(m3.x); acc0.y += v3 * bfhi(m3.x);
            acc0.z += v3 * bflo(m3.y); acc0.w += v3 * bfhi(m3.y);
            acc1.x += v3 * bflo(m3.z); acc1.y += v3 * bfhi(m3.z);
            acc1.z += v3 * bflo(m3.w); acc1.w += v3 * bfhi(m3.w);

            acc0.x += v4 * bflo(m4.x); acc0.y += v4 * bfhi(m4.x);
            acc0.z += v4 * bflo(m4.y); acc0.w += v4 * bfhi(m4.y);
            acc1.x += v4 * bflo(m4.z); acc1.y += v4 * bfhi(m4.z);
            acc1.z += v4 * bflo(m4.w); acc1.w += v4 * bfhi(m4.w);

            acc0.x += v5 * bflo(m5.x); acc0.y += v5 * bfhi(m5.x);
            acc0.z += v5 * bflo(m5.y); acc0.w += v5 * bfhi(m5.y);
            acc1.x += v5 * bflo(m5.z); acc1.y += v5 * bfhi(m5.z);
            acc1.z += v5 * bflo(m5.w); acc1.w += v5 * bfhi(m5.w);

            acc0.x += v6 * bflo(m6.x); acc0.y += v6 * bfhi(m6.x);
            acc0.z += v6 * bflo(m6.y); acc0.w += v6 * bfhi(m6.y);
            acc1.x += v6 * bflo(m6.z); acc1.y += v6 * bfhi(m6.z);
            acc1.z += v6 * bflo(m6.w); acc1.w += v6 * bfhi(m6.w);

            acc0.x += v7 * bflo(m7.x); acc0.y += v7 * bfhi(m7.x);
            acc0.z += v7 * bflo(m7.y); acc0.w += v7 * bfhi(m7.y);
            acc1.x += v7 * bflo(m7.z); acc1.y += v7 * bfhi(m7.z);
            acc1.z += v7 * bflo(m7.w); acc1.w += v7 * bfhi(m7.w);
        }
        __builtin_amdgcn_wave_barrier();  // next chunk's writes after reads
    }

    if (live) {
        // nontemporal stores: out is touch-once, keep it out of L2
        long ob = (long)node * 16 + 2 * t;    // features [8t, 8t+8)
        __builtin_nontemporal_store(*(const v4f*)&acc0, (v4f*)&out4[ob]);
        __builtin_nontemporal_store(*(const v4f*)&acc1, (v4f*)&out4[ob + 1]);
    }
}

// ------------------------------------------------------------------ host ---
extern "C" void kernel_launch(void* const* d_in, const int* in_sizes, int n_in,
                              void* d_out, int out_size, void* d_ws, size_t ws_size,
                              hipStream_t stream) {
    const int*   rows   = (const int*)d_in[0];
    const int*   cols   = (const int*)d_in[1];
    const float* vals   = (const float*)d_in[2];
    const float* embeds = (const float*)d_in[3];
    float4*      out4   = (float4*)d_out;

    const int n_edges = in_sizes[0];
    const int n_nodes = out_size / D;                 // 100000
    const int n_feat  = in_sizes[3];                  // 6,400,000

    uint4* ebf_table = (uint4*)d_ws;                  // 12.8 MB bf16 table

    // 1) convert-only prep
    int n8         = n_feat / 8;                      // 800,000 groups
    int cvt_blocks = (n8 + 255) / 256;                // 3125
    prep_kernel<<<cvt_blocks, 256, 0, stream>>>(
        (const uint4*)embeds, ebf_table, n8);

    // 2) node-centric SpMM: 8 nodes/wave, 4 waves/block, search-based bounds
    int blocks = (n_nodes + 31) / 32;                 // 3125
    spmm_node_kernel<<<blocks, 256, 0, stream>>>(
        rows, cols, vals, ebf_table, out4, n_edges, n_nodes);
}

// Round 7
// 119.754 us; speedup vs baseline: 1.6853x; 1.0842x over previous
//
#include <hip/hip_runtime.h>

// GCN SpMM: out[i,d] = sum_{e: rows[e]==i} vals[e] * embeds[cols[e], d]
// rows sorted ascending. E=1.6M, N=100k, D=64.
//
// Round 14: R9 structure restored + NT streaming hints.
// Evidence through R13:
//   - Fixed harness overhead (ws poison fill + out fill + graph gaps) = 72 us
//     regardless of dispatch count or ws use (R12: 149-77=72; R13: 129.8-58=72).
//     Objective is purely prep+spmm.
//   - spmm is fabric-BW-bound on L2-miss bytes at ~2.7-2.8 TB/s random-sector
//     service (R12: f32 185 MB = 77 us; R13: bf16 85 MB = 51.5 us incl search).
//     bf16 table halves miss traffic -> keep it (absmax 0.0625, known-pass).
//   - In-kernel binary-search bounds (R13) cost ~10 us: 21-deep dependent-load
//     chain per wave, unhidden at block-generation starts + rows refetch
//     traffic. REVERTED to row_ptr built in prep (parallel, amortized).
//   - NT hints on touch-once streams (cols/vals staging loads, out stores)
//     kept: they avoid evicting the 16x-reused table from the 4-MiB L2.
//   - spmm geometry (proven R8/R9): 8-lane subgroups (8 nodes/wave), lane t
//     owns 16 B of the 128-B bf16 row -> 1 gather instr covers 8 rows;
//     wave-private LDS staging of cols/vals; unroll-8 gather pipeline.

constexpr int D = 64;

typedef float v4f __attribute__((ext_vector_type(4)));

__device__ __forceinline__ unsigned bf16rnd(unsigned u) {
    // round-to-nearest-even f32 -> bf16 (low 16 bits)
    return (u + 0x7FFFu + ((u >> 16) & 1u)) >> 16;
}
__device__ __forceinline__ float bflo(unsigned w) {
    union { unsigned u; float f; } x; x.u = w << 16; return x.f;
}
__device__ __forceinline__ float bfhi(unsigned w) {
    union { unsigned u; float f; } x; x.u = w & 0xFFFF0000u; return x.f;
}

// ---- prep (merged): f32->bf16 table + CSR row_ptr -----------------------
__global__ __launch_bounds__(256) void prep_kernel(
    const uint4* __restrict__ src,   // f32 embeds as uint4 (2 per 8-float group)
    uint4* __restrict__ dst,         // bf16 table as uint4 (8 bf16)
    int n8,
    const int* __restrict__ rows, int* __restrict__ row_ptr,
    int n_edges, int n_nodes, int cvt_blocks)
{
    if ((int)blockIdx.x < cvt_blocks) {
        int i = blockIdx.x * 256 + threadIdx.x;
        if (i >= n8) return;
        uint4 a = src[2 * i];
        uint4 b = src[2 * i + 1];
        uint4 o;
        o.x = bf16rnd(a.x) | (bf16rnd(a.y) << 16);
        o.y = bf16rnd(a.z) | (bf16rnd(a.w) << 16);
        o.z = bf16rnd(b.x) | (bf16rnd(b.y) << 16);
        o.w = bf16rnd(b.z) | (bf16rnd(b.w) << 16);
        dst[i] = o;
    } else {
        int e = (blockIdx.x - cvt_blocks) * 256 + threadIdx.x;
        if (e >= n_edges) return;
        int r_cur  = rows[e];
        int r_prev = (e == 0) ? -1 : rows[e - 1];
        for (int r = r_prev + 1; r <= r_cur; ++r) row_ptr[r] = e;
        if (e == n_edges - 1)
            for (int r = r_cur + 1; r <= n_nodes; ++r) row_ptr[r] = n_edges;
    }
}

// ---- spmm: node-centric, bf16 gathers, row_ptr bounds -------------------
__global__ __launch_bounds__(256, 4) void spmm_node_kernel(
    const int* __restrict__ row_ptr,
    const int* __restrict__ cols,
    const float* __restrict__ vals,
    const uint4* __restrict__ ebf4,       // bf16 [N,64]: row = 8 uint4
    float4* __restrict__ out4,            // [N,16] float4 view
    int n_nodes)
{
    constexpr int CHUNK = 256;            // edges staged per wave per pass
    __shared__ int   s_cols[4][CHUNK];    // 4 waves/block, wave-private
    __shared__ float s_vals[4][CHUNK];

    const int lane = threadIdx.x & 63;
    const int t    = lane & 7;            // 16B chunk within row (0..7)
    const int s    = lane >> 3;           // subgroup (node) within wave (0..7)
    const int w    = threadIdx.x >> 6;    // wave within block
    const int wave = blockIdx.x * 4 + w;
    const int node = wave * 8 + s;
    if (node >= n_nodes) return;

    const int nb    = wave * 8;
    const int nbhi  = (nb + 8 <= n_nodes) ? nb + 8 : n_nodes;
    const int wbase = row_ptr[nb];        // wave's contiguous edge span
    const int wend  = row_ptr[nbhi];
    const int lo    = row_ptr[node];
    const int hi    = row_ptr[node + 1];

    float4 acc0 = make_float4(0.f, 0.f, 0.f, 0.f);
    float4 acc1 = make_float4(0.f, 0.f, 0.f, 0.f);

    for (int cbase = wbase; cbase < wend; cbase += CHUNK) {
        // cooperative, coalesced staging; NT (touch-once streams, keep L2
        // for the 16x-reused table)
        #pragma unroll
        for (int j = 0; j < CHUNK; j += 64) {
            if (cbase + j >= wend) break;         // wave-uniform early out
            int idx = cbase + j + lane;
            if (idx < wend) {
                s_cols[w][j + lane] = __builtin_nontemporal_load(&cols[idx]);
                s_vals[w][j + lane] = __builtin_nontemporal_load(&vals[idx]);
            }
        }
        __builtin_amdgcn_wave_barrier();  // pin ds_writes before ds_reads

        const int cend = (cbase + CHUNK < wend) ? cbase + CHUNK : wend;
        int e0 = (lo > cbase) ? lo : cbase;       // this node's slice of chunk
        int e1 = (hi < cend)  ? hi : cend;

        for (int e = e0; e < e1; e += 8) {
            const int last = e1 - 1;
            int i0 = e - cbase;
            int i1 = ((e + 1 <= last) ? e + 1 : last) - cbase;
            int i2 = ((e + 2 <= last) ? e + 2 : last) - cbase;
            int i3 = ((e + 3 <= last) ? e + 3 : last) - cbase;
            int i4 = ((e + 4 <= last) ? e + 4 : last) - cbase;
            int i5 = ((e + 5 <= last) ? e + 5 : last) - cbase;
            int i6 = ((e + 6 <= last) ? e + 6 : last) - cbase;
            int i7 = ((e + 7 <= last) ? e + 7 : last) - cbase;

            int c0 = s_cols[w][i0], c1 = s_cols[w][i1];
            int c2 = s_cols[w][i2], c3 = s_cols[w][i3];
            int c4 = s_cols[w][i4], c5 = s_cols[w][i5];
            int c6 = s_cols[w][i6], c7 = s_cols[w][i7];

            float v0 = s_vals[w][i0];
            float v1 = (e + 1 < e1) ? s_vals[w][i1] : 0.f;
            float v2 = (e + 2 < e1) ? s_vals[w][i2] : 0.f;
            float v3 = (e + 3 < e1) ? s_vals[w][i3] : 0.f;
            float v4 = (e + 4 < e1) ? s_vals[w][i4] : 0.f;
            float v5 = (e + 5 < e1) ? s_vals[w][i5] : 0.f;
            float v6 = (e + 6 < e1) ? s_vals[w][i6] : 0.f;
            float v7 = (e + 7 < e1) ? s_vals[w][i7] : 0.f;

            // 8 independent dwordx4 gathers in flight; each covers 8 rows
            uint4 m0 = ebf4[c0 * 8 + t];
            uint4 m1 = ebf4[c1 * 8 + t];
            uint4 m2 = ebf4[c2 * 8 + t];
            uint4 m3 = ebf4[c3 * 8 + t];
            uint4 m4 = ebf4[c4 * 8 + t];
            uint4 m5 = ebf4[c5 * 8 + t];
            uint4 m6 = ebf4[c6 * 8 + t];
            uint4 m7 = ebf4[c7 * 8 + t];

            acc0.x += v0 * bflo(m0.x); acc0.y += v0 * bfhi(m0.x);
            acc0.z += v0 * bflo(m0.y); acc0.w += v0 * bfhi(m0.y);
            acc1.x += v0 * bflo(m0.z); acc1.y += v0 * bfhi(m0.z);
            acc1.z += v0 * bflo(m0.w); acc1.w += v0 * bfhi(m0.w);

            acc0.x += v1 * bflo(m1.x); acc0.y += v1 * bfhi(m1.x);
            acc0.z += v1 * bflo(m1.y); acc0.w += v1 * bfhi(m1.y);
            acc1.x += v1 * bflo(m1.z); acc1.y += v1 * bfhi(m1.z);
            acc1.z += v1 * bflo(m1.w); acc1.w += v1 * bfhi(m1.w);

            acc0.x += v2 * bflo(m2.x); acc0.y += v2 * bfhi(m2.x);
            acc0.z += v2 * bflo(m2.y); acc0.w += v2 * bfhi(m2.y);
            acc1.x += v2 * bflo(m2.z); acc1.y += v2 * bfhi(m2.z);
            acc1.z += v2 * bflo(m2.w); acc1.w += v2 * bfhi(m2.w);

            acc0.x += v3 * bflo(m3.x); acc0.y += v3 * bfhi(m3.x);
            acc0.z += v3 * bflo(m3.y); acc0.w += v3 * bfhi(m3.y);
            acc1.x += v3 * bflo(m3.z); acc1.y += v3 * bfhi(m3.z);
            acc1.z += v3 * bflo(m3.w); acc1.w += v3 * bfhi(m3.w);

            acc0.x += v4 * bflo(m4.x); acc0.y += v4 * bfhi(m4.x);
            acc0.z += v4 * bflo(m4.y); acc0.w += v4 * bfhi(m4.y);
            acc1.x += v4 * bflo(m4.z); acc1.y += v4 * bfhi(m4.z);
            acc1.z += v4 * bflo(m4.w); acc1.w += v4 * bfhi(m4.w);

            acc0.x += v5 * bflo(m5.x); acc0.y += v5 * bfhi(m5.x);
            acc0.z += v5 * bflo(m5.y); acc0.w += v5 * bfhi(m5.y);
            acc1.x += v5 * bflo(m5.z); acc1.y += v5 * bfhi(m5.z);
            acc1.z += v5 * bflo(m5.w); acc1.w += v5 * bfhi(m5.w);

            acc0.x += v6 * bflo(m6.x); acc0.y += v6 * bfhi(m6.x);
            acc0.z += v6 * bflo(m6.y); acc0.w += v6 * bfhi(m6.y);
            acc1.x += v6 * bflo(m6.z); acc1.y += v6 * bfhi(m6.z);
            acc1.z += v6 * bflo(m6.w); acc1.w += v6 * bfhi(m6.w);

            acc0.x += v7 * bflo(m7.x); acc0.y += v7 * bfhi(m7.x);
            acc0.z += v7 * bflo(m7.y); acc0.w += v7 * bfhi(m7.y);
            acc1.x += v7 * bflo(m7.z); acc1.y += v7 * bfhi(m7.z);
            acc1.z += v7 * bflo(m7.w); acc1.w += v7 * bfhi(m7.w);
        }
        __builtin_amdgcn_wave_barrier();  // next chunk's writes after reads
    }

    // NT stores: out is touch-once, keep it out of L2
    long ob = (long)node * 16 + 2 * t;    // features [8t, 8t+8)
    __builtin_nontemporal_store(*(const v4f*)&acc0, (v4f*)&out4[ob]);
    __builtin_nontemporal_store(*(const v4f*)&acc1, (v4f*)&out4[ob + 1]);
}

// ------------------------------------------------------------------ host ---
extern "C" void kernel_launch(void* const* d_in, const int* in_sizes, int n_in,
                              void* d_out, int out_size, void* d_ws, size_t ws_size,
                              hipStream_t stream) {
    const int*   rows   = (const int*)d_in[0];
    const int*   cols   = (const int*)d_in[1];
    const float* vals   = (const float*)d_in[2];
    const float* embeds = (const float*)d_in[3];
    float4*      out4   = (float4*)d_out;

    const int n_edges = in_sizes[0];
    const int n_nodes = out_size / D;                 // 100000
    const int n_feat  = in_sizes[3];                  // 6,400,000

    char*  ws        = (char*)d_ws;
    uint4* ebf_table = (uint4*)ws;                    // 12.8 MB bf16 table
    int*   row_ptr   = (int*)(ws + (size_t)n_feat * 2);

    // 1) merged prep: f32->bf16 table + CSR row pointers
    int n8         = n_feat / 8;                      // 800,000 groups
    int cvt_blocks = (n8 + 255) / 256;                // 3125
    int row_blocks = (n_edges + 255) / 256;           // 6250
    prep_kernel<<<cvt_blocks + row_blocks, 256, 0, stream>>>(
        (const uint4*)embeds, ebf_table, n8,
        rows, row_ptr, n_edges, n_nodes, cvt_blocks);

    // 2) node-centric SpMM: 8 nodes/wave, 4 waves/block
    int waves  = (n_nodes + 7) / 8;                   // 12500
    int blocks = (waves + 3) / 4;                     // 3125
    spmm_node_kernel<<<blocks, 256, 0, stream>>>(
        row_ptr, cols, vals, ebf_table, out4, n_nodes);
}